// Round 8
// baseline (284.557 us; speedup 1.0000x reference)
//
#include <hip/hip_runtime.h>

// Problem constants (from reference)
#define NV      163842      // vertices
#define CIN     64
#define KN      7
#define NKMAX   (NV * KN)   // 1,146,894 valid neigh entries
#define KDIM    448         // 7*64
#define KSTEPS  14          // 448 / 32
#define VPC     16          // vertices per chunk

typedef short  short8 __attribute__((ext_vector_type(8)));
typedef float  f32x4  __attribute__((ext_vector_type(4)));
typedef float  f32x2  __attribute__((ext_vector_type(2)));

static __device__ __forceinline__ unsigned int pack_bf16(float a, float b) {
#if __has_builtin(__builtin_amdgcn_cvt_pk_bf16_f32)
    typedef __bf16 bf16x2 __attribute__((ext_vector_type(2)));
    union { bf16x2 v; unsigned int u; } cv;
    cv.v = __builtin_amdgcn_cvt_pk_bf16_f32(a, b);
    return cv.u;
#else
    unsigned int ua = __float_as_uint(a);
    unsigned int ub = __float_as_uint(b);
    ua = (ua + 0x7FFFu + ((ua >> 16) & 1u)) >> 16;
    ub = (ub + 0x7FFFu + ((ub >> 16) & 1u)) & 0xFFFF0000u;
    return ua | ub;
#endif
}

// ---- pre-pass: x [N][C][B] fp32 -> x_t [B][N][C] bf16 (de-interleave + cast) ----
__global__ __launch_bounds__(256)
void xcast(const float* __restrict__ x, unsigned int* __restrict__ xt, int nf4)
{
    const int f = blockIdx.x * 256 + threadIdx.x;   // float4 index over x
    if (f >= nf4) return;                           // nf4 = NV*32
    const f32x4 g = __builtin_nontemporal_load(&((const f32x4*)x)[f]);
    const int v = f >> 5;
    const int r = f & 31;                           // u32 slot; c0 = 2r
    xt[v * 32 + r]           = pack_bf16(g[0], g[2]); // batch 0: c0, c0+1
    xt[NV * 32 + v * 32 + r] = pack_bf16(g[1], g[3]); // batch 1
}

// ---- main: ZERO-LDS design. Gather lands directly in MFMA A-fragment layout.
// A[m=ncol][k=s*32+kgrp*8+j] = xt[bb=ncol&1][ neigh[(vb+lv)*7 + (s>>1)] ]
//                               [c=(s&1)*32+kgrp*8+j],  lv = mt*8 + (ncol>>1)
// => one aligned 16B global load per A-fragment. No LDS, no barriers.
// Wave w of 4: mt = w&1 (16 M-rows), oh = w>>1 (32 O-cols, bfrag[14][2]).
// Cross-chunk pipeline: while chunk c computes, A-frags for c+G and indices
// for c+2G are in flight.
__global__ __launch_bounds__(256, 2)
void onering_mfma_bf16(const unsigned short* __restrict__ xt,
                       const int* __restrict__ neigh,
                       const float* __restrict__ W,
                       const float* __restrict__ bias,
                       float* __restrict__ out,
                       int nchunks)
{
    const int tid  = threadIdx.x;
    const int lane = tid & 63;
    const int w    = tid >> 6;
    const int mt   = w & 1;          // M-tile (rows mt*16 .. mt*16+15)
    const int oh   = w >> 1;         // O-half (cols oh*32 .. oh*32+31)
    const int ncol = lane & 15;
    const int kgrp = lane >> 4;
    const int G    = gridDim.x;

    // ---- persistent B fragments: W (fp32) -> bf16, register-resident (112 VGPR) ----
    short8 bfrag[KSTEPS][2];
#pragma unroll
    for (int s = 0; s < KSTEPS; ++s) {
#pragma unroll
        for (int ot = 0; ot < 2; ++ot) {
            const int o  = oh * 32 + ot * 16 + ncol;
            const int kb = s * 32 + kgrp * 8;
            const float4* wp = (const float4*)(W + o * KDIM + kb);
            float4 w0 = wp[0];
            float4 w1 = wp[1];
            union { short8 v; unsigned int u[4]; } pk;
            pk.u[0] = pack_bf16(w0.x, w0.y);
            pk.u[1] = pack_bf16(w0.z, w0.w);
            pk.u[2] = pack_bf16(w1.x, w1.y);
            pk.u[3] = pack_bf16(w1.z, w1.w);
            bfrag[s][ot] = pk.v;
        }
    }
    const float bias0 = bias[oh * 32 + ncol];
    const float bias1 = bias[oh * 32 + 16 + ncol];

    // per-lane gather geometry
    const int lv  = mt * 8 + (ncol >> 1);          // local vertex 0..15 (per mt: 8)
    const int bb  = ncol & 1;                       // batch
    const unsigned short* xtb = xt + (size_t)bb * (NV * 64);
    const int nbase = lv * KN;                      // + vb*KN + kappa

    const int ch0 = blockIdx.x;
    short8 R[KSTEPS];   // A-frags for current chunk
    int    I[KN];       // neigh indices for NEXT chunk (c+G)

    // ---- prologue ----
    {
        int Ic[KN];
#pragma unroll
        for (int k2 = 0; k2 < KN; ++k2) {
            int gi = ch0 * (VPC * KN) + nbase + k2;
            Ic[k2] = __builtin_nontemporal_load(&neigh[gi < NKMAX ? gi : 0]);
        }
#pragma unroll
        for (int s = 0; s < KSTEPS; ++s) {
            const int c0 = (s & 1) * 32 + kgrp * 8;
            R[s] = *(const short8*)(xtb + Ic[s >> 1] * 64 + c0);
        }
#pragma unroll
        for (int k2 = 0; k2 < KN; ++k2) {
            int gi = (ch0 + G) * (VPC * KN) + nbase + k2;
            I[k2] = __builtin_nontemporal_load(&neigh[gi < NKMAX ? gi : 0]);
        }
    }

    for (int ch = ch0; ch < nchunks; ch += G) {
        const int vb = ch * VPC;

        // ---- compute current chunk; refill R with chunk ch+G as we go ----
        f32x4 acc0 = {0.f, 0.f, 0.f, 0.f};
        f32x4 acc1 = {0.f, 0.f, 0.f, 0.f};
#pragma unroll
        for (int s = 0; s < KSTEPS; ++s) {
            const short8 a = R[s];
            acc0 = __builtin_amdgcn_mfma_f32_16x16x32_bf16(a, bfrag[s][0], acc0, 0, 0, 0);
            acc1 = __builtin_amdgcn_mfma_f32_16x16x32_bf16(a, bfrag[s][1], acc1, 0, 0, 0);
            const int c0 = (s & 1) * 32 + kgrp * 8;
            R[s] = *(const short8*)(xtb + I[s >> 1] * 64 + c0);   // chunk ch+G
        }

        // ---- indices for chunk ch+2G ----
#pragma unroll
        for (int k2 = 0; k2 < KN; ++k2) {
            int gi = (ch + 2 * G) * (VPC * KN) + nbase + k2;
            I[k2] = __builtin_nontemporal_load(&neigh[gi < NKMAX ? gi : 0]);
        }

        // ---- store: C/D col=ncol, row=kgrp*4+j ; (j,j+1)=(b0,b1) -> float2 ----
        // lanes (ncol 0..15) x 8B = 128B contiguous per kgrp => fully coalesced
#pragma unroll
        for (int jp = 0; jp < 2; ++jp) {
            const int n = vb + mt * 8 + kgrp * 2 + jp;
            if (n < NV) {
                const int o0 = oh * 32 + ncol;
                f32x2 v0 = {acc0[2 * jp] + bias0, acc0[2 * jp + 1] + bias0};
                f32x2 v1 = {acc1[2 * jp] + bias1, acc1[2 * jp + 1] + bias1};
                __builtin_nontemporal_store(v0, (f32x2*)(out + n * 128 + o0 * 2));
                __builtin_nontemporal_store(v1, (f32x2*)(out + n * 128 + (o0 + 16) * 2));
            }
        }
    }
}

// ---- fallback (ws too small): fp32-gather kernel, LDS-based ----
#define ROWS    32
#define ASTRIDE 456
__global__ __launch_bounds__(256, 4)
void onering_mfma_f32(const float* __restrict__ x,
                      const int* __restrict__ neigh,
                      const float* __restrict__ W,
                      const float* __restrict__ bias,
                      float* __restrict__ out,
                      int nchunks)
{
    __shared__ unsigned short A_lds[ROWS * ASTRIDE];
    const int tid  = threadIdx.x;
    const int lane = tid & 63;
    const int w    = tid >> 6;
    const int ncol = lane & 15;
    const int kgrp = lane >> 4;

    short8 bfrag[KSTEPS];
    {
        const int o = w * 16 + ncol;
#pragma unroll
        for (int s = 0; s < KSTEPS; ++s) {
            const int kb = s * 32 + kgrp * 8;
            const float4* wp = (const float4*)(W + o * KDIM + kb);
            float4 w0 = wp[0];
            float4 w1 = wp[1];
            union { short8 v; unsigned int u[4]; } pk;
            pk.u[0] = pack_bf16(w0.x, w0.y);
            pk.u[1] = pack_bf16(w0.z, w0.w);
            pk.u[2] = pack_bf16(w1.x, w1.y);
            pk.u[3] = pack_bf16(w1.z, w1.w);
            bfrag[s] = pk.v;
        }
    }
    const float biasv = bias[w * 16 + ncol];
    const int off4  = tid & 31;
    const int sbase = tid >> 5;

    for (int ch = blockIdx.x; ch < nchunks; ch += gridDim.x) {
        const int vb = ch * VPC;
        __syncthreads();
#pragma unroll
        for (int i = 0; i < 14; ++i) {
            const int s  = sbase + 8 * i;
            const int lv = s / 7;
            const int k  = s - lv * 7;
            const int n  = vb + lv;
            int vi = 0;
            if (n < NV) vi = neigh[n * KN + k];
            const float4 g = ((const float4*)x)[vi * 32 + off4];
            const int base = k * 64 + 2 * off4;
            ((unsigned int*)A_lds)[((lv * 2)     * ASTRIDE + base) >> 1] = pack_bf16(g.x, g.z);
            ((unsigned int*)A_lds)[((lv * 2 + 1) * ASTRIDE + base) >> 1] = pack_bf16(g.y, g.w);
        }
        __syncthreads();
        f32x4 acc0 = {0.f, 0.f, 0.f, 0.f};
        f32x4 acc1 = {0.f, 0.f, 0.f, 0.f};
#pragma unroll
        for (int s = 0; s < KSTEPS; ++s) {
            const int kb = s * 32 + kgrp * 8;
            const short8 a0 = *(const short8*)&A_lds[ncol * ASTRIDE + kb];
            const short8 a1 = *(const short8*)&A_lds[(16 + ncol) * ASTRIDE + kb];
            acc0 = __builtin_amdgcn_mfma_f32_16x16x32_bf16(a0, bfrag[s], acc0, 0, 0, 0);
            acc1 = __builtin_amdgcn_mfma_f32_16x16x32_bf16(a1, bfrag[s], acc1, 0, 0, 0);
        }
        const int o = w * 16 + ncol;
#pragma unroll
        for (int j = 0; j < 4; ++j) {
            const int r = kgrp * 4 + j;
            {
                const int lv = r >> 1, b2 = r & 1, n = vb + lv;
                if (n < NV) out[n * 128 + o * 2 + b2] = acc0[j] + biasv;
            }
            {
                const int m = 16 + r;
                const int lv = m >> 1, b2 = m & 1, n = vb + lv;
                if (n < NV) out[n * 128 + o * 2 + b2] = acc1[j] + biasv;
            }
        }
    }
}

extern "C" void kernel_launch(void* const* d_in, const int* in_sizes, int n_in,
                              void* d_out, int out_size, void* d_ws, size_t ws_size,
                              hipStream_t stream) {
    const float* x     = (const float*)d_in[0];
    const int*   neigh = (const int*)d_in[1];   // int64 in ref -> int32 from harness
    const float* W     = (const float*)d_in[2];
    const float* bias  = (const float*)d_in[3];
    float*       out   = (float*)d_out;

    const int nchunks = (NV + VPC - 1) / VPC;   // 10241
    const size_t need = (size_t)2 * NV * 64 * sizeof(unsigned short);  // 41.9 MB

    if (ws_size >= need) {
        unsigned short* xt = (unsigned short*)d_ws;
        const int nf4 = NV * 32;
        xcast<<<dim3((nf4 + 255) / 256), dim3(256), 0, stream>>>(x, (unsigned int*)xt, nf4);
        onering_mfma_bf16<<<dim3(2048), dim3(256), 0, stream>>>(xt, neigh, W, bias, out, nchunks);
    } else {
        onering_mfma_f32<<<dim3(2560), dim3(256), 0, stream>>>(x, neigh, W, bias, out, nchunks);
    }
}